// Round 7
// baseline (191.646 us; speedup 1.0000x reference)
//
#include <hip/hip_runtime.h>

constexpr int IN_F  = 256;
constexpr int OUT_F = 512;
constexpr int BATCH = 2048;

// pack[(o,i)] = {p0,p1,p2,p3 | q1,q2,q3,w} : one aligned 32B record.
__global__ __launch_bounds__(256) void prep_pack8_kernel(
    const float* __restrict__ p, const float* __restrict__ q,
    const float* __restrict__ w, float4* __restrict__ pk, int n) {
    int t = blockIdx.x * 256 + threadIdx.x;
    if (t < n) {
        pk[2 * t]     = make_float4(p[4 * t], p[4 * t + 1], p[4 * t + 2], p[4 * t + 3]);
        pk[2 * t + 1] = make_float4(q[3 * t], q[3 * t + 1], q[3 * t + 2], w[t]);
    }
}

// x3[b,i] = RN(x^3) via f64, once per (b,i).
__global__ __launch_bounds__(256) void prep_x3_kernel(
    const float* __restrict__ x, float* __restrict__ x3, int n) {
    int t = blockIdx.x * 256 + threadIdx.x;
    if (t < n) {
        const double xd = (double)x[t];
        x3[t] = (float)(xd * xd * xd);   // RN(x^3) == powf(x,3)
    }
}

// Block = 64 batches (lanes) x 8 outputs; waves split the i-dimension.
// Coefficients travel global -> reg -> wave-private LDS double-buffer ->
// broadcast ds_read_b128 (T14 reg-staged, barrier-free: tiles are
// wave-private and the DS pipe is in-order per wave). This replaces the
// SMEM s_load stream (K$-miss-bound, SGPR-depth-limited) with a deeply
// pipelined VMEM stream and puts all fma operands in VGPRs (no SGPR-
// operand moves).
//
// NUMERICS (bit-exact vs np reference -- DO NOT REORDER, verified R3-R6,
// absmax 768 vs threshold 5.7e5):
//   x^2 = RN(x*x); x^3 = RN(x^3) via f64 table; S = fmaf chain ascending p
//   starting from RN(c1*x); Q' = (1+S)+1e-6 as two separate adds; division
//   via rcp (relative-error-only).
template <int MODE>   // 2 = LDS-staged + x3 table; 1 = s_load packed; 0 = raw
__global__ __launch_bounds__(256, 8) void kan_kernel(
    const float*  __restrict__ x,
    const float4* __restrict__ Pc,    // (O, I) of {p0,p1,p2,p3}
    const float*  __restrict__ Qc,    // (O, I, 3) raw (MODE 0)
    const float4* __restrict__ PK,    // (O, I) 2x float4 records (MODE >= 1)
    const float*  __restrict__ X3,    // (B, I) RN(x^3) table (MODE 2)
    const float*  __restrict__ W,     // (O, I) raw (MODE 0)
    const float*  __restrict__ bias,  // (O)
    float* __restrict__ out)          // (B, O)
{
#pragma clang fp contract(off)       // protect the explicit add sequence
    const int lane  = threadIdx.x & 63;
    const int wave  = __builtin_amdgcn_readfirstlane(threadIdx.x >> 6);
    const int b     = blockIdx.x * 64 + lane;
    const int o0    = blockIdx.y * 8;
    const int ibase = wave * 64;      // this wave's i-slice

    float acc[8] = {0.f, 0.f, 0.f, 0.f, 0.f, 0.f, 0.f, 0.f};
    const float* xrow  = x + (size_t)b * IN_F + ibase;
    const float* x3row = (MODE == 2) ? (X3 + (size_t)b * IN_F + ibase) : nullptr;

    __shared__ float4 cbuf[4][2][64];  // [wave][parity][1KB tile]  = 8KB
    __shared__ float  red[4 * 64 * 8]; //                            = 8KB

    if (MODE == 2) {
        // Stage addressing: lane covers o-chunk c = lane>>3, 16B piece
        // sub = lane&7 of the (4-record x 32B) group for that o.
        const int c   = lane >> 3;
        const int sub = lane & 7;
        const size_t gbase = 2 * ((size_t)(o0 + c) * IN_F) + sub;

        // Prologue: tile 0 -> LDS, tile 1 -> regs, x-step 0 -> regs.
        float4 st = PK[gbase + 2 * (size_t)(ibase + 0)];
        cbuf[wave][0][lane] = st;
        st = PK[gbase + 2 * (size_t)(ibase + 4)];
        float4 xq  = *reinterpret_cast<const float4*>(xrow);
        float4 x3q = *reinterpret_cast<const float4*>(x3row);

        for (int k = 0; k < 16; ++k) {
            const int par = k & 1;
            if (k < 15) {
                cbuf[wave][par ^ 1][lane] = st;            // tile k+1 -> LDS
                if (k < 14)
                    st = PK[gbase + 2 * (size_t)(ibase + 4 * (k + 2))];
            }
            float x1[4]  = {xq.x, xq.y, xq.z, xq.w};
            float x3v[4] = {x3q.x, x3q.y, x3q.z, x3q.w};
            if (k < 15) {                                   // prefetch x k+1
                xq  = *reinterpret_cast<const float4*>(xrow  + 4 * (k + 1));
                x3q = *reinterpret_cast<const float4*>(x3row + 4 * (k + 1));
            }
            float x2[4];
#pragma unroll
            for (int j = 0; j < 4; ++j) x2[j] = x1[j] * x1[j];  // RN(x^2)

            const float4* cb = cbuf[wave][par];
#pragma unroll
            for (int oo = 0; oo < 8; ++oo) {
#pragma unroll
                for (int j = 0; j < 4; ++j) {
                    const float4 pa = cb[(oo * 4 + j) * 2];     // broadcast
                    const float4 pb = cb[(oo * 4 + j) * 2 + 1]; // ds_read
                    // ---- S_Q : einsum fmaf chain, accum starts at 0 ----
                    float t = pb.x * x1[j];            // == fma(q1,x1,0)
                    t = fmaf(pb.y, x2[j], t);
                    t = fmaf(pb.z, x3v[j], t);
                    float Qv = 1.0f + t;               // Sterbenz-exact
                    float Qp = Qv + 1e-6f;
                    // ---- S_P : same einsum chain ----
                    float s = fmaf(pa.y, x1[j], pa.x);
                    s = fmaf(pa.z, x2[j], s);
                    s = fmaf(pa.w, x3v[j], s);
                    const float r = __builtin_amdgcn_rcpf(Qp);
                    acc[oo] = fmaf(s, r, acc[oo]);        // rational term
                    acc[oo] = fmaf(pb.w, x1[j], acc[oo]); // base matmul
                }
            }
        }
    } else {
        for (int ic = 0; ic < 64; ic += 4) {
            const float4 xq = *reinterpret_cast<const float4*>(xrow + ic);
            float x1[4] = {xq.x, xq.y, xq.z, xq.w};
            float x2[4], x3v[4];
#pragma unroll
            for (int j = 0; j < 4; ++j) {
                x2[j] = x1[j] * x1[j];
                const double xd = (double)x1[j];
                x3v[j] = (float)(xd * xd * xd);
            }
            const int rowi = ibase + ic;
#pragma unroll
            for (int oo = 0; oo < 8; ++oo) {
                const int rowbase = (o0 + oo) * IN_F + rowi;
#pragma unroll
                for (int j = 0; j < 4; ++j) {
                    float p0, p1, p2, p3, q1, q2, q3, wv;
                    if (MODE == 1) {
                        const float4 pa = PK[2 * (size_t)(rowbase + j)];
                        const float4 pb = PK[2 * (size_t)(rowbase + j) + 1];
                        p0 = pa.x; p1 = pa.y; p2 = pa.z; p3 = pa.w;
                        q1 = pb.x; q2 = pb.y; q3 = pb.z; wv = pb.w;
                    } else {
                        const float4 pc = Pc[rowbase + j];
                        const float* qp = Qc + (size_t)(rowbase + j) * 3;
                        p0 = pc.x; p1 = pc.y; p2 = pc.z; p3 = pc.w;
                        q1 = qp[0]; q2 = qp[1]; q3 = qp[2];
                        wv = W[rowbase + j];
                    }
                    float t = q1 * x1[j];
                    t = fmaf(q2, x2[j], t);
                    t = fmaf(q3, x3v[j], t);
                    float Qv = 1.0f + t;
                    float Qp = Qv + 1e-6f;
                    float s = fmaf(p1, x1[j], p0);
                    s = fmaf(p2, x2[j], s);
                    s = fmaf(p3, x3v[j], s);
                    const float r = __builtin_amdgcn_rcpf(Qp);
                    acc[oo] = fmaf(s, r, acc[oo]);
                    acc[oo] = fmaf(wv, x1[j], acc[oo]);
                }
            }
        }
    }

    // ---- cross-wave reduction: red[wave][lane][o] ----
    float4* dst = reinterpret_cast<float4*>(&red[(wave * 64 + lane) * 8]);
    dst[0] = make_float4(acc[0], acc[1], acc[2], acc[3]);
    dst[1] = make_float4(acc[4], acc[5], acc[6], acc[7]);
    __syncthreads();

#pragma unroll
    for (int k = 0; k < 2; ++k) {
        const int idx = threadIdx.x + k * 256;     // idx = bb*8 + o
        float s = red[idx] + red[512 + idx];       // wave order 0,1,2,3
        s = s + red[1024 + idx];
        s = s + red[1536 + idx];
        const int bb = idx >> 3, o = idx & 7;
        s = s + bias[o0 + o];
        out[(size_t)(blockIdx.x * 64 + bb) * OUT_F + o0 + o] = s;
    }
}

extern "C" void kernel_launch(void* const* d_in, const int* in_sizes, int n_in,
                              void* d_out, int out_size, void* d_ws, size_t ws_size,
                              hipStream_t stream) {
    const float* x    = (const float*)d_in[0];
    const float* Pc   = (const float*)d_in[1];
    const float* Qc   = (const float*)d_in[2];
    const float* W    = (const float*)d_in[3];
    const float* bias = (const float*)d_in[4];
    float* out = (float*)d_out;

    const int n  = OUT_F * IN_F;          // 131072 (o,i) records
    const int nx = BATCH * IN_F;          // 524288 (b,i) x-powers
    const size_t pk_bytes = (size_t)n * 32;
    dim3 grid(BATCH / 64, OUT_F / 8);     // 2048 blocks = 8/CU

    if (ws_size >= pk_bytes + (size_t)nx * sizeof(float)) {
        float4* pk = (float4*)d_ws;
        float*  x3 = (float*)((char*)d_ws + pk_bytes);
        prep_pack8_kernel<<<(n + 255) / 256, 256, 0, stream>>>(Pc, Qc, W, pk, n);
        prep_x3_kernel<<<(nx + 255) / 256, 256, 0, stream>>>(x, x3, nx);
        kan_kernel<2><<<grid, 256, 0, stream>>>(
            x, (const float4*)Pc, Qc, pk, x3, W, bias, out);
    } else if (ws_size >= pk_bytes) {
        float4* pk = (float4*)d_ws;
        prep_pack8_kernel<<<(n + 255) / 256, 256, 0, stream>>>(Pc, Qc, W, pk, n);
        kan_kernel<1><<<grid, 256, 0, stream>>>(
            x, (const float4*)Pc, Qc, pk, nullptr, W, bias, out);
    } else {
        kan_kernel<0><<<grid, 256, 0, stream>>>(
            x, (const float4*)Pc, Qc, nullptr, nullptr, W, bias, out);
    }
}

// Round 8
// 120.218 us; speedup vs baseline: 1.5942x; 1.5942x over previous
//
#include <hip/hip_runtime.h>

constexpr int IN_F  = 256;
constexpr int OUT_F = 512;
constexpr int BATCH = 2048;

// pack[(o,i)] = {p0,p1,p2,p3 | q1,q2,q3,w} : one aligned 32B record so the
// hot loop issues uniform scalar loads (s_load_dwordx8) per element.
__global__ __launch_bounds__(256) void prep_pack8_kernel(
    const float* __restrict__ p, const float* __restrict__ q,
    const float* __restrict__ w, float4* __restrict__ pk, int n) {
    int t = blockIdx.x * 256 + threadIdx.x;
    if (t < n) {
        pk[2 * t]     = make_float4(p[4 * t], p[4 * t + 1], p[4 * t + 2], p[4 * t + 3]);
        pk[2 * t + 1] = make_float4(q[3 * t], q[3 * t + 1], q[3 * t + 2], w[t]);
    }
}

// x3[b,i] = RN(x^3) via f64, once per (b,i).
__global__ __launch_bounds__(256) void prep_x3_kernel(
    const float* __restrict__ x, float* __restrict__ x3, int n) {
    int t = blockIdx.x * 256 + threadIdx.x;
    if (t < n) {
        const double xd = (double)x[t];
        x3[t] = (float)(xd * xd * xd);   // RN(x^3) == powf(x,3)
    }
}

// Block = 64 batches (lanes) x 8 outputs; waves split the i-dimension; each
// wave computes all 8 outputs (x-powers amortized 8x). Coefficients via
// wave-uniform scalar loads (R6 structure -- R7's LDS staging spilled to
// scratch and regressed 1.8x; do not revisit). 9-stride padded LDS
// reduction (conflict-free). Grid = 2048 blocks = 8 blocks/CU.
//
// NUMERICS (bit-exact vs np reference -- DO NOT REORDER, verified R3-R7,
// absmax 768 vs threshold 5.7e5):
//   x^2 = RN(x*x); x^3 = RN(x^3) via f64 table; S = fmaf chain ascending p
//   starting from RN(c1*x); Q' = (1+S)+1e-6 as two separate adds; division
//   via rcp (relative-error-only).
template <int MODE>   // 2 = packed + x3 table; 1 = packed; 0 = raw arrays
__global__ __launch_bounds__(256, 8) void kan_kernel(
    const float*  __restrict__ x,
    const float4* __restrict__ Pc,    // (O, I) of {p0,p1,p2,p3}
    const float*  __restrict__ Qc,    // (O, I, 3) raw (MODE 0)
    const float4* __restrict__ PK,    // (O, I) 2x float4 records (MODE >= 1)
    const float*  __restrict__ X3,    // (B, I) RN(x^3) table (MODE 2)
    const float*  __restrict__ W,     // (O, I) raw (MODE 0)
    const float*  __restrict__ bias,  // (O)
    float* __restrict__ out)          // (B, O)
{
#pragma clang fp contract(off)       // protect the explicit add sequence
    const int lane  = threadIdx.x & 63;
    const int wave  = __builtin_amdgcn_readfirstlane(threadIdx.x >> 6);
    const int b     = blockIdx.x * 64 + lane;
    const int o0    = blockIdx.y * 8;
    const int ibase = wave * 64;      // this wave's i-slice

    float acc[8] = {0.f, 0.f, 0.f, 0.f, 0.f, 0.f, 0.f, 0.f};
    const float* xrow  = x + (size_t)b * IN_F + ibase;
    const float* x3row = (MODE == 2) ? (X3 + (size_t)b * IN_F + ibase) : nullptr;

#pragma unroll 2     // two i-steps in flight -> deeper s_load pipelining
    for (int ic = 0; ic < 64; ic += 4) {
        const float4 xq = *reinterpret_cast<const float4*>(xrow + ic);
        float x1[4] = {xq.x, xq.y, xq.z, xq.w};
        float x2[4], x3v[4];
        if (MODE == 2) {
            const float4 x3q = *reinterpret_cast<const float4*>(x3row + ic);
            x3v[0] = x3q.x; x3v[1] = x3q.y; x3v[2] = x3q.z; x3v[3] = x3q.w;
#pragma unroll
            for (int j = 0; j < 4; ++j) x2[j] = x1[j] * x1[j];  // RN(x^2)
        } else {
#pragma unroll
            for (int j = 0; j < 4; ++j) {
                x2[j] = x1[j] * x1[j];
                const double xd = (double)x1[j];
                x3v[j] = (float)(xd * xd * xd);
            }
        }
        const int rowi = ibase + ic;
#pragma unroll
        for (int oo = 0; oo < 8; ++oo) {
            const int rowbase = (o0 + oo) * IN_F + rowi;
#pragma unroll
            for (int j = 0; j < 4; ++j) {          // 4 contiguous 32B records
                float p0, p1, p2, p3, q1, q2, q3, wv;
                if (MODE >= 1) {
                    const float4 pa = PK[2 * (size_t)(rowbase + j)];
                    const float4 pb = PK[2 * (size_t)(rowbase + j) + 1];
                    p0 = pa.x; p1 = pa.y; p2 = pa.z; p3 = pa.w;
                    q1 = pb.x; q2 = pb.y; q3 = pb.z; wv = pb.w;
                } else {
                    const float4 pc = Pc[rowbase + j];
                    const float* qp = Qc + (size_t)(rowbase + j) * 3;
                    p0 = pc.x; p1 = pc.y; p2 = pc.z; p3 = pc.w;
                    q1 = qp[0]; q2 = qp[1]; q3 = qp[2];
                    wv = W[rowbase + j];
                }
                // ---- S_Q : einsum fmaf chain, accum starts at 0 ----
                float t = q1 * x1[j];              // == fma(q1,x1,0)
                t = fmaf(q2, x2[j], t);
                t = fmaf(q3, x3v[j], t);
                float Qv = 1.0f + t;               // Sterbenz-exact near pole
                float Qp = Qv + 1e-6f;
                // ---- S_P : same einsum chain ----
                float s = fmaf(p1, x1[j], p0);
                s = fmaf(p2, x2[j], s);
                s = fmaf(p3, x3v[j], s);
                const float r = __builtin_amdgcn_rcpf(Qp);
                acc[oo] = fmaf(s, r, acc[oo]);       // rational term
                acc[oo] = fmaf(wv, x1[j], acc[oo]);  // fused base matmul
            }
        }
    }

    // ---- cross-wave reduction: red[wave][lane][9] (pad -> conflict-free) ----
    __shared__ float red[4 * 64 * 9];
    {
        float* dst = &red[(wave * 64 + lane) * 9];
#pragma unroll
        for (int v = 0; v < 8; ++v) dst[v] = acc[v];
    }
    __syncthreads();

#pragma unroll
    for (int k = 0; k < 2; ++k) {
        const int idx = threadIdx.x + k * 256;     // idx = bb*8 + o
        const int bb = idx >> 3, o = idx & 7;
        const int e = bb * 9 + o;
        float s = red[e] + red[576 + e];           // wave order 0,1,2,3
        s = s + red[1152 + e];
        s = s + red[1728 + e];
        s = s + bias[o0 + o];
        out[(size_t)(blockIdx.x * 64 + bb) * OUT_F + o0 + o] = s;
    }
}

extern "C" void kernel_launch(void* const* d_in, const int* in_sizes, int n_in,
                              void* d_out, int out_size, void* d_ws, size_t ws_size,
                              hipStream_t stream) {
    const float* x    = (const float*)d_in[0];
    const float* Pc   = (const float*)d_in[1];
    const float* Qc   = (const float*)d_in[2];
    const float* W    = (const float*)d_in[3];
    const float* bias = (const float*)d_in[4];
    float* out = (float*)d_out;

    const int n  = OUT_F * IN_F;          // 131072 (o,i) records
    const int nx = BATCH * IN_F;          // 524288 (b,i) x-powers
    const size_t pk_bytes = (size_t)n * 32;
    dim3 grid(BATCH / 64, OUT_F / 8);     // 2048 blocks = 8/CU

    if (ws_size >= pk_bytes + (size_t)nx * sizeof(float)) {
        float4* pk = (float4*)d_ws;
        float*  x3 = (float*)((char*)d_ws + pk_bytes);
        prep_pack8_kernel<<<(n + 255) / 256, 256, 0, stream>>>(Pc, Qc, W, pk, n);
        prep_x3_kernel<<<(nx + 255) / 256, 256, 0, stream>>>(x, x3, nx);
        kan_kernel<2><<<grid, 256, 0, stream>>>(
            x, (const float4*)Pc, Qc, pk, x3, W, bias, out);
    } else if (ws_size >= pk_bytes) {
        float4* pk = (float4*)d_ws;
        prep_pack8_kernel<<<(n + 255) / 256, 256, 0, stream>>>(Pc, Qc, W, pk, n);
        kan_kernel<1><<<grid, 256, 0, stream>>>(
            x, (const float4*)Pc, Qc, pk, nullptr, W, bias, out);
    } else {
        kan_kernel<0><<<grid, 256, 0, stream>>>(
            x, (const float4*)Pc, Qc, nullptr, nullptr, W, bias, out);
    }
}